// Round 13
// baseline (229.400 us; speedup 1.0000x reference)
//
#include <hip/hip_runtime.h>

// LIF recurrence, T=4, TAU=1.0, THRESH=1.0.
// mem = mem + x[t]; spike = (mem - 1 > 0); mem = spike ? 0 : mem.
//
// v7: guaranteed deep read bursts via global_load_lds. v3-v5 tried to build
// per-wave MLP in registers; the allocator collapsed/spilled every time
// (VGPR pinned 32-36). v6 (block-contiguous chunks) gave only ~6%.
// global_load_lds is the one load path with ZERO register cost: each wave
// fires 8 x 1KB loads back-to-back into its PRIVATE LDS slice (no cross-wave
// sharing -> no barrier), then consumes plane-by-plane behind counted
// s_waitcnt vmcnt(6) — stores are always younger in the vmcnt queue, so
// consuming plane t never waits on store retirement (v3's idea, enforced).
// 8KB in flight per wave, ~160KB/CU at 5 blocks/CU (LDS 32KB/block).
// NT stores kept (proven no-RFO, time-neutral).

#define LIF_T 4
#define CHUNK_F4 512   // float4 per plane per block (8KB/plane, 32KB LDS total)

typedef float f32x4 __attribute__((ext_vector_type(4)));

#define AS1 __attribute__((address_space(1)))
#define AS3 __attribute__((address_space(3)))

__device__ __forceinline__ f32x4 lif_step(f32x4& mem, f32x4 xt) {
    mem.x += xt.x;
    mem.y += xt.y;
    mem.z += xt.z;
    mem.w += xt.w;
    f32x4 sp;
    sp.x = (mem.x > 1.0f) ? 1.0f : 0.0f;
    sp.y = (mem.y > 1.0f) ? 1.0f : 0.0f;
    sp.z = (mem.z > 1.0f) ? 1.0f : 0.0f;
    sp.w = (mem.w > 1.0f) ? 1.0f : 0.0f;
    mem.x = (sp.x > 0.f) ? 0.f : mem.x;
    mem.y = (sp.y > 0.f) ? 0.f : mem.y;
    mem.z = (sp.z > 0.f) ? 0.f : mem.z;
    mem.w = (sp.w > 0.f) ? 0.f : mem.w;
    return sp;
}

__global__ __launch_bounds__(256) void
lif_spike_kernel(const float* __restrict__ x, float* __restrict__ out, int n_vec) {
    __shared__ f32x4 lds[LIF_T][CHUNK_F4];

    const int tid  = threadIdx.x;
    const int wave = tid >> 6;       // 0..3
    const int lane = tid & 63;
    const int b0   = blockIdx.x * CHUNK_F4;   // block's first float4 per plane

    const f32x4* __restrict__ xv = reinterpret_cast<const f32x4*>(x);
    f32x4* __restrict__ ov = reinterpret_cast<f32x4*>(out);

    if (b0 + CHUNK_F4 <= n_vec) {
        // ---- fast path (exact cover: 4096 blocks x 512 == n_vec) ----
        // Burst phase: 8 fire-and-forget 1KB loads per wave, zero VGPR cost.
        // Wave w owns float4 [w*128, w*128+128) of each plane's slice.
#pragma unroll
        for (int t = 0; t < LIF_T; ++t) {
#pragma unroll
            for (int s = 0; s < 2; ++s) {
                const int l4 = wave * 128 + s * 64;
                const f32x4* g = xv + (size_t)t * n_vec + b0 + l4 + lane;
                __builtin_amdgcn_global_load_lds(
                    (const AS1 void*)g, (AS3 void*)&lds[t][l4], 16, 0, 0);
            }
        }

        f32x4 mem[2];
        mem[0] = (f32x4){0.f, 0.f, 0.f, 0.f};
        mem[1] = (f32x4){0.f, 0.f, 0.f, 0.f};

        // Consume plane-by-plane. vmcnt queue at plane t:
        // [L(2t), L(2t+1), ..., L7, S...] -> waiting vmcnt(6) retires exactly
        // the two oldest (this plane's loads); the 2t stores issued so far are
        // youngest and never block the wait.
#pragma unroll
        for (int t = 0; t < LIF_T; ++t) {
            asm volatile("s_waitcnt vmcnt(6)" ::: "memory");
            __builtin_amdgcn_sched_barrier(0);
#pragma unroll
            for (int c = 0; c < 2; ++c) {
                const int l4 = wave * 128 + c * 64 + lane;
                f32x4 xt = lds[t][l4];
                f32x4 sp = lif_step(mem[c], xt);
                __builtin_nontemporal_store(sp, &ov[(size_t)t * n_vec + b0 + l4]);
            }
        }
    } else {
        // ---- tail path (not taken in the exact bench shape) ----
        f32x4 memc[2];
        memc[0] = (f32x4){0.f, 0.f, 0.f, 0.f};
        memc[1] = (f32x4){0.f, 0.f, 0.f, 0.f};
#pragma unroll
        for (int t = 0; t < LIF_T; ++t) {
#pragma unroll
            for (int c = 0; c < 2; ++c) {
                const int idx = b0 + wave * 128 + c * 64 + lane;
                if (idx < n_vec) {
                    f32x4 sp = lif_step(memc[c], xv[(size_t)t * n_vec + idx]);
                    __builtin_nontemporal_store(sp, &ov[(size_t)t * n_vec + idx]);
                }
            }
        }
    }
}

extern "C" void kernel_launch(void* const* d_in, const int* in_sizes, int n_in,
                              void* d_out, int out_size, void* d_ws, size_t ws_size,
                              hipStream_t stream) {
    const float* x = (const float*)d_in[0];
    float* out = (float*)d_out;

    int n = out_size / LIF_T;      // elements per timestep (8,388,608)
    int n_vec = n / 4;             // float4 groups per timestep (2,097,152)

    const int block = 256;
    int grid = (n_vec + CHUNK_F4 - 1) / CHUNK_F4;   // 4096
    lif_spike_kernel<<<grid, block, 0, stream>>>(x, out, n_vec);
}

// Round 14
// 227.691 us; speedup vs baseline: 1.0075x; 1.0075x over previous
//
#include <hip/hip_runtime.h>

// LIF recurrence, T=4, TAU=1.0, THRESH=1.0.
// mem = mem + x[t]; spike = (mem - 1 > 0); mem = spike ? 0 : mem.
//
// v8: v6 structure, REGULAR (cacheable) stores — the NT/regular A/B at the
// contiguous structure. Ledger: MLP depth 1/2/4/8-guaranteed (v1/v2/v6/v7)
// all ~77-84us; concurrency exonerated. All fast references (fill 6.6 TB/s,
// m13 copy 6.29) use the CACHEABLE write path: L2/L3 absorb stores and the
// DRAM controller drains them in long batches decoupled from reads. Our NT
// stores force fine-grained R/W interleave at HBM (bus turnaround per 4KB
// switch). v1-vs-v2 tested NT only at the old strided structure.
// Signals: dur 55-65 => write-decoupling wins, keep regular. FETCH jumps
// ~+131MB => RFO real, revert NT and declare pattern ceiling. Neutral with
// FETCH flat => declare ~77us ceiling (arithmetic: 268MB @ ~3.4 TB/s vs
// 4.9-6.3 TB/s refs; every software axis measured null).

#define LIF_T 4
#define CHUNKS 4

typedef float f32x4 __attribute__((ext_vector_type(4)));

__device__ __forceinline__ f32x4 lif_step(f32x4& mem, f32x4 xt) {
    mem.x += xt.x;
    mem.y += xt.y;
    mem.z += xt.z;
    mem.w += xt.w;
    f32x4 sp;
    sp.x = (mem.x > 1.0f) ? 1.0f : 0.0f;
    sp.y = (mem.y > 1.0f) ? 1.0f : 0.0f;
    sp.z = (mem.z > 1.0f) ? 1.0f : 0.0f;
    sp.w = (mem.w > 1.0f) ? 1.0f : 0.0f;
    mem.x = (sp.x > 0.f) ? 0.f : mem.x;
    mem.y = (sp.y > 0.f) ? 0.f : mem.y;
    mem.z = (sp.z > 0.f) ? 0.f : mem.z;
    mem.w = (sp.w > 0.f) ? 0.f : mem.w;
    return sp;
}

__global__ __launch_bounds__(256) void
lif_spike_kernel(const float* __restrict__ x, float* __restrict__ out, int n_vec) {
    // Block b owns float4 indices [b*1024, b*1024+1024) of every plane:
    // 4 contiguous 16KB streams per plane set.
    const int base = blockIdx.x * (256 * CHUNKS) + threadIdx.x;
    const f32x4* __restrict__ xv = reinterpret_cast<const f32x4*>(x);
    f32x4* __restrict__ ov = reinterpret_cast<f32x4*>(out);

    if (base + (CHUNKS - 1) * 256 < n_vec) {
        // ---- fast path (exact cover in the bench shape: 2048*1024 == n_vec) ----
        f32x4 mem[CHUNKS];
#pragma unroll
        for (int c = 0; c < CHUNKS; ++c) mem[c] = (f32x4){0.f, 0.f, 0.f, 0.f};

#pragma unroll
        for (int t = 0; t < LIF_T; ++t) {
            const size_t p = (size_t)t * n_vec + base;
            f32x4 xt[CHUNKS];
#pragma unroll
            for (int c = 0; c < CHUNKS; ++c) xt[c] = xv[p + c * 256];
#pragma unroll
            for (int c = 0; c < CHUNKS; ++c) {
                f32x4 sp = lif_step(mem[c], xt[c]);
                ov[p + c * 256] = sp;   // cacheable store: L2/L3 write-back path
            }
        }
    } else {
        // ---- tail path (not taken in the exact bench shape) ----
        f32x4 memc[CHUNKS];
#pragma unroll
        for (int c = 0; c < CHUNKS; ++c) memc[c] = (f32x4){0.f, 0.f, 0.f, 0.f};
#pragma unroll
        for (int t = 0; t < LIF_T; ++t) {
#pragma unroll
            for (int c = 0; c < CHUNKS; ++c) {
                int idx = base + c * 256;
                if (idx < n_vec) {
                    f32x4 sp = lif_step(memc[c], xv[(size_t)t * n_vec + idx]);
                    ov[(size_t)t * n_vec + idx] = sp;
                }
            }
        }
    }
}

extern "C" void kernel_launch(void* const* d_in, const int* in_sizes, int n_in,
                              void* d_out, int out_size, void* d_ws, size_t ws_size,
                              hipStream_t stream) {
    const float* x = (const float*)d_in[0];
    float* out = (float*)d_out;

    int n = out_size / LIF_T;      // elements per timestep (8,388,608)
    int n_vec = n / 4;             // float4 groups per timestep (2,097,152)

    const int block = 256;
    int grid = (n_vec + block * CHUNKS - 1) / (block * CHUNKS);  // 2048
    lif_spike_kernel<<<grid, block, 0, stream>>>(x, out, n_vec);
}

// Round 15
// 217.281 us; speedup vs baseline: 1.0558x; 1.0479x over previous
//
#include <hip/hip_runtime.h>

// LIF recurrence, T=4, TAU=1.0, THRESH=1.0.
// mem = mem + x[t]; spike = (mem - 1 > 0); mem = spike ? 0 : mem.
//
// v9: clean HBM read streams via nontemporal LOADS. Ledger through v8:
// MLP depth 1/2/4/8, store type x2 structures, contiguity, occupancy,
// schedule, LDS staging — all null; kernel pinned ~77us = 3.4 TB/s while
// the structurally-identical float4 copy does 6.29 TB/s (m13). Remaining
// anomaly: FETCH=65.5MB = exactly half the input — L3 serves alternating
// lines, so the DRAM read stream is HOLE-Y (fragmented misses, no long
// sequential runs -> activate cost per fragment). Copy benches are full-miss
// and stream cleanly. Fix: NT loads bypass L2/L3 -> full-miss contiguous
// read stream (FETCH should jump to ~134MB as confirmation); regular
// cacheable stores (v8: equal to NT) leave L3 to batch the write stream.
// Single variable vs v8: load path.

#define LIF_T 4
#define CHUNKS 4

typedef float f32x4 __attribute__((ext_vector_type(4)));

__device__ __forceinline__ f32x4 lif_step(f32x4& mem, f32x4 xt) {
    mem.x += xt.x;
    mem.y += xt.y;
    mem.z += xt.z;
    mem.w += xt.w;
    f32x4 sp;
    sp.x = (mem.x > 1.0f) ? 1.0f : 0.0f;
    sp.y = (mem.y > 1.0f) ? 1.0f : 0.0f;
    sp.z = (mem.z > 1.0f) ? 1.0f : 0.0f;
    sp.w = (mem.w > 1.0f) ? 1.0f : 0.0f;
    mem.x = (sp.x > 0.f) ? 0.f : mem.x;
    mem.y = (sp.y > 0.f) ? 0.f : mem.y;
    mem.z = (sp.z > 0.f) ? 0.f : mem.z;
    mem.w = (sp.w > 0.f) ? 0.f : mem.w;
    return sp;
}

__global__ __launch_bounds__(256) void
lif_spike_kernel(const float* __restrict__ x, float* __restrict__ out, int n_vec) {
    // Block b owns float4 indices [b*1024, b*1024+1024) of every plane:
    // 16KB-contiguous read/write windows per plane (v6 structure).
    const int base = blockIdx.x * (256 * CHUNKS) + threadIdx.x;
    const f32x4* __restrict__ xv = reinterpret_cast<const f32x4*>(x);
    f32x4* __restrict__ ov = reinterpret_cast<f32x4*>(out);

    if (base + (CHUNKS - 1) * 256 < n_vec) {
        // ---- fast path (exact cover in the bench shape: 2048*1024 == n_vec) ----
        f32x4 mem[CHUNKS];
#pragma unroll
        for (int c = 0; c < CHUNKS; ++c) mem[c] = (f32x4){0.f, 0.f, 0.f, 0.f};

#pragma unroll
        for (int t = 0; t < LIF_T; ++t) {
            const size_t p = (size_t)t * n_vec + base;
            f32x4 xt[CHUNKS];
            // NT loads: bypass L2/L3 -> full-miss, contiguous HBM read stream
#pragma unroll
            for (int c = 0; c < CHUNKS; ++c)
                xt[c] = __builtin_nontemporal_load(&xv[p + c * 256]);
#pragma unroll
            for (int c = 0; c < CHUNKS; ++c) {
                f32x4 sp = lif_step(mem[c], xt[c]);
                ov[p + c * 256] = sp;   // cacheable store: L3 batches the writes
            }
        }
    } else {
        // ---- tail path (not taken in the exact bench shape) ----
        f32x4 memc[CHUNKS];
#pragma unroll
        for (int c = 0; c < CHUNKS; ++c) memc[c] = (f32x4){0.f, 0.f, 0.f, 0.f};
#pragma unroll
        for (int t = 0; t < LIF_T; ++t) {
#pragma unroll
            for (int c = 0; c < CHUNKS; ++c) {
                int idx = base + c * 256;
                if (idx < n_vec) {
                    f32x4 xt = __builtin_nontemporal_load(&xv[(size_t)t * n_vec + idx]);
                    f32x4 sp = lif_step(memc[c], xt);
                    ov[(size_t)t * n_vec + idx] = sp;
                }
            }
        }
    }
}

extern "C" void kernel_launch(void* const* d_in, const int* in_sizes, int n_in,
                              void* d_out, int out_size, void* d_ws, size_t ws_size,
                              hipStream_t stream) {
    const float* x = (const float*)d_in[0];
    float* out = (float*)d_out;

    int n = out_size / LIF_T;      // elements per timestep (8,388,608)
    int n_vec = n / 4;             // float4 groups per timestep (2,097,152)

    const int block = 256;
    int grid = (n_vec + block * CHUNKS - 1) / (block * CHUNKS);  // 2048
    lif_spike_kernel<<<grid, block, 0, stream>>>(x, out, n_vec);
}